// Round 1
// baseline (303.947 us; speedup 1.0000x reference)
//
#include <hip/hip_runtime.h>

#define N_NODES 10000
#define N_EDGES 160000
#define IN_DIM 128
#define HID 16
#define HEADS 50
#define OUT_DIM 10
#define N_GRAPHS 8
#define NHID (HEADS * HID) /* 800 */

// ---- bf16 helpers (self-contained, RNE) ----
static __device__ __forceinline__ unsigned short f2bf(float f) {
    union { float f; unsigned u; } v; v.f = f;
    unsigned u = v.u;
    unsigned r = (u + 0x7fffu + ((u >> 16) & 1u)) >> 16;
    return (unsigned short)r;
}
static __device__ __forceinline__ float bf2f(unsigned short s) {
    union { unsigned u; float f; } v; v.u = ((unsigned)s) << 16;
    return v.f;
}

// ---- K1: xp = x(10000x128) @ W(128x800), fp32 accum, bf16 store ----
__global__ __launch_bounds__(256) void gemm_kernel(const float* __restrict__ x,
                                                   const float* __restrict__ W,
                                                   unsigned short* __restrict__ xp) {
    __shared__ float As[64][64];  // As[k][m] (A transposed for b128 reads along M)
    __shared__ float Bs[64][64];  // Bs[k][n]
    const int tid = threadIdx.x;
    const int m0 = blockIdx.y * 64;
    const int n0 = blockIdx.x * 64;
    const int tx = tid & 15, ty = tid >> 4;
    float acc[4][4] = {};
    const int am = tid & 63;         // A loader: m within tile
    const int ak = (tid >> 6) * 16;  // A loader: k4 group base
    const int bn = (tid & 15) * 4;   // B loader: n within tile
    const int bk = tid >> 4;         // B loader: k row base

    for (int kk = 0; kk < IN_DIM; kk += 64) {
        const int gm = m0 + am;
#pragma unroll
        for (int i = 0; i < 4; i++) {
            int k4 = ak + i * 4;
            float4 v = make_float4(0.f, 0.f, 0.f, 0.f);
            if (gm < N_NODES) v = *(const float4*)(x + gm * IN_DIM + kk + k4);
            As[k4 + 0][am] = v.x; As[k4 + 1][am] = v.y;
            As[k4 + 2][am] = v.z; As[k4 + 3][am] = v.w;
        }
#pragma unroll
        for (int i = 0; i < 4; i++) {
            int k = bk + i * 16;
            float4 v = make_float4(0.f, 0.f, 0.f, 0.f);
            if (n0 + bn < NHID) v = *(const float4*)(W + (kk + k) * NHID + n0 + bn);
            *(float4*)&Bs[k][bn] = v;
        }
        __syncthreads();
#pragma unroll
        for (int k = 0; k < 64; k++) {
            float4 a = *(const float4*)&As[k][ty * 4];
            float4 b = *(const float4*)&Bs[k][tx * 4];
            float av[4] = {a.x, a.y, a.z, a.w};
            float bv[4] = {b.x, b.y, b.z, b.w};
#pragma unroll
            for (int i = 0; i < 4; i++)
#pragma unroll
                for (int j = 0; j < 4; j++) acc[i][j] += av[i] * bv[j];
        }
        __syncthreads();
    }
#pragma unroll
    for (int i = 0; i < 4; i++) {
        int gm = m0 + ty * 4 + i;
        int gn = n0 + tx * 4;
        if (gm < N_NODES && gn < NHID) {
            ushort4 o;
            o.x = f2bf(acc[i][0]); o.y = f2bf(acc[i][1]);
            o.z = f2bf(acc[i][2]); o.w = f2bf(acc[i][3]);
            *(ushort4*)(xp + gm * NHID + gn) = o;  // 8B aligned
        }
    }
}

// ---- K2: alpha_s[n,h] = xp[n,h,:].a_src[h,:]; alpha_d likewise ----
__global__ __launch_bounds__(256) void alpha_kernel(const unsigned short* __restrict__ xp,
                                                    const float* __restrict__ a_src,
                                                    const float* __restrict__ a_dst,
                                                    float* __restrict__ as_out,
                                                    float* __restrict__ ad_out) {
    int tid = blockIdx.x * 256 + threadIdx.x;
    if (tid >= N_NODES * HEADS) return;
    int n = tid / HEADS, h = tid % HEADS;
    const uint4* row4 = (const uint4*)(xp + n * NHID + h * HID);  // 16B aligned
    uint4 r0 = row4[0], r1 = row4[1];
    unsigned uu[8] = {r0.x, r0.y, r0.z, r0.w, r1.x, r1.y, r1.z, r1.w};
    float s = 0.f, d = 0.f;
#pragma unroll
    for (int q = 0; q < 8; q++) {
        float v0 = bf2f((unsigned short)(uu[q] & 0xffffu));
        float v1 = bf2f((unsigned short)(uu[q] >> 16));
        s += v0 * a_src[h * HID + 2 * q] + v1 * a_src[h * HID + 2 * q + 1];
        d += v0 * a_dst[h * HID + 2 * q] + v1 * a_dst[h * HID + 2 * q + 1];
    }
    as_out[tid] = s;
    ad_out[tid] = d;
}

// ---- K3: CSR build (count / scan / scatter) ----
__global__ void count_kernel(const int* __restrict__ ei, int* __restrict__ cnt) {
    int e = blockIdx.x * 256 + threadIdx.x;
    if (e < N_EDGES) atomicAdd(&cnt[ei[N_EDGES + e]], 1);
}

__global__ __launch_bounds__(1024) void scan_kernel(const int* __restrict__ cnt,
                                                    int* __restrict__ offs,
                                                    int* __restrict__ curs) {
    __shared__ int lds[1024];
    const int tid = threadIdx.x;
    const int base = tid * 10;
    int local[10];
    int s = 0;
#pragma unroll
    for (int i = 0; i < 10; i++) {
        int idx = base + i;
        int v = (idx < N_NODES) ? cnt[idx] : 0;
        local[i] = s;
        s += v;
    }
    lds[tid] = s;
    __syncthreads();
    for (int off = 1; off < 1024; off <<= 1) {
        int v = (tid >= off) ? lds[tid - off] : 0;
        __syncthreads();
        lds[tid] += v;
        __syncthreads();
    }
    int excl = lds[tid] - s;
    for (int i = 0; i < 10; i++) {
        int idx = base + i;
        if (idx < N_NODES) {
            int o = excl + local[i];
            offs[idx] = o;
            curs[idx] = o;
        }
    }
}

__global__ void scatter_kernel(const int* __restrict__ ei, int* __restrict__ curs,
                               int* __restrict__ ssrc) {
    int e = blockIdx.x * 256 + threadIdx.x;
    if (e < N_EDGES) {
        int d = ei[N_EDGES + e];
        int pos = atomicAdd(&curs[d], 1);
        ssrc[pos] = ei[e];
    }
}

// ---- K4: per-dst-node softmax-weighted aggregation + head mean + pool scatter ----
__global__ __launch_bounds__(256) void agg_kernel(const unsigned short* __restrict__ xp,
                                                  const float* __restrict__ as,
                                                  const float* __restrict__ ad,
                                                  const int* __restrict__ offs,
                                                  const int* __restrict__ cnt,
                                                  const int* __restrict__ ssrc,
                                                  const int* __restrict__ batch,
                                                  const float* __restrict__ bias,
                                                  float* __restrict__ gsum,
                                                  float* __restrict__ gcnt) {
    const int n = blockIdx.x;
    const int t = threadIdx.x;
    __shared__ float ad_l[HEADS];
    __shared__ float w_l[HEADS];
    __shared__ float den_l[HEADS];
    __shared__ float acc_l[NHID];
    if (t < HEADS) ad_l[t] = ad[n * HEADS + t];
    float acc0 = 0.f, acc1 = 0.f, acc2 = 0.f, acc3 = 0.f;
    float den = 0.f;
    const int start = offs[n];
    const int ecnt = cnt[n];
    const int h = t >> 2;  // thread t<200 handles (h = t/4, c0 = (t%4)*4) -> element 4t
    __syncthreads();
    for (int e = 0; e <= ecnt; e++) {  // last iteration = self loop
        const int src = (e < ecnt) ? ssrc[start + e] : n;
        if (t < HEADS) {
            float l = as[src * HEADS + t] + ad_l[t];
            l = (l > 0.f) ? l : 0.2f * l;  // leaky relu
            float wv = expf(l);            // softmax without max-shift: logits bounded
            w_l[t] = wv;
            den += wv;
        }
        __syncthreads();
        if (t < 200) {
            uint2 uu = *(const uint2*)((const unsigned*)(xp + src * NHID) + t * 2);
            float wv = w_l[h];
            acc0 += wv * bf2f((unsigned short)(uu.x & 0xffffu));
            acc1 += wv * bf2f((unsigned short)(uu.x >> 16));
            acc2 += wv * bf2f((unsigned short)(uu.y & 0xffffu));
            acc3 += wv * bf2f((unsigned short)(uu.y >> 16));
        }
        __syncthreads();
    }
    if (t < HEADS) den_l[t] = den;
    __syncthreads();
    if (t < 200) {
        float inv = 1.f / den_l[h];
        acc_l[t * 4 + 0] = acc0 * inv;
        acc_l[t * 4 + 1] = acc1 * inv;
        acc_l[t * 4 + 2] = acc2 * inv;
        acc_l[t * 4 + 3] = acc3 * inv;
    }
    __syncthreads();
    if (t < HID) {
        float s = 0.f;
#pragma unroll
        for (int hh = 0; hh < HEADS; hh++) s += acc_l[hh * HID + t];
        float hv = s * (1.f / HEADS) + bias[t];
        atomicAdd(&gsum[batch[n] * HID + t], hv);
    }
    if (t == 0) atomicAdd(&gcnt[batch[n]], 1.f);
}

// ---- K5: pooled = gsum/cnt; out = pooled @ fc_w + fc_b ----
__global__ void final_kernel(const float* __restrict__ gsum, const float* __restrict__ gcnt,
                             const float* __restrict__ fc_w, const float* __restrict__ fc_b,
                             float* __restrict__ out) {
    int t = threadIdx.x;
    if (t < N_GRAPHS * OUT_DIM) {
        int g = t / OUT_DIM, o = t % OUT_DIM;
        float c = gcnt[g];
        c = (c > 1.f) ? c : 1.f;
        float inv = 1.f / c;
        float s = fc_b[o];
#pragma unroll
        for (int k = 0; k < HID; k++) s += gsum[g * HID + k] * inv * fc_w[k * OUT_DIM + o];
        out[t] = s;
    }
}

// ---- workspace layout (bytes) ----
#define XP_OFF 0              /* 10000*800*2  = 16,000,000 */
#define AS_OFF 16000000       /* 10000*50*4   =  2,000,000 */
#define AD_OFF 18000000       /* 10000*50*4   =  2,000,000 */
#define SSRC_OFF 20000000     /* 160000*4     =    640,000 */
#define OFFS_OFF 20640000     /* 10000*4      =     40,000 */
#define CURS_OFF 20680000     /* 10000*4      =     40,000 */
#define CNT_OFF 20720000      /* 10000*4      =     40,000  (zeroed) */
#define GSUM_OFF 20760000     /* 8*16*4       =        512  (zeroed) */
#define GCNT_OFF 20760512     /* 8*4          =         32  (zeroed) */

extern "C" void kernel_launch(void* const* d_in, const int* in_sizes, int n_in,
                              void* d_out, int out_size, void* d_ws, size_t ws_size,
                              hipStream_t stream) {
    const float* x = (const float*)d_in[0];
    const int* ei = (const int*)d_in[1];     // [2, E] int32 (JAX x64 disabled)
    const int* batch = (const int*)d_in[2];
    const float* W = (const float*)d_in[4];
    const float* a_src = (const float*)d_in[5];
    const float* a_dst = (const float*)d_in[6];
    const float* bias = (const float*)d_in[7];
    const float* fc_w = (const float*)d_in[8];
    const float* fc_b = (const float*)d_in[9];
    float* out = (float*)d_out;

    char* ws = (char*)d_ws;
    unsigned short* xp = (unsigned short*)(ws + XP_OFF);
    float* as = (float*)(ws + AS_OFF);
    float* ad = (float*)(ws + AD_OFF);
    int* ssrc = (int*)(ws + SSRC_OFF);
    int* offs = (int*)(ws + OFFS_OFF);
    int* curs = (int*)(ws + CURS_OFF);
    int* cntc = (int*)(ws + CNT_OFF);
    float* gsum = (float*)(ws + GSUM_OFF);
    float* gcnt = (float*)(ws + GCNT_OFF);

    // zero counts + pooled sums (ws is poisoned 0xAA before every launch)
    hipMemsetAsync(ws + CNT_OFF, 0, 40000 + 512 + 32, stream);

    gemm_kernel<<<dim3((NHID + 63) / 64, (N_NODES + 63) / 64), 256, 0, stream>>>(x, W, xp);
    alpha_kernel<<<(N_NODES * HEADS + 255) / 256, 256, 0, stream>>>(xp, a_src, a_dst, as, ad);
    count_kernel<<<(N_EDGES + 255) / 256, 256, 0, stream>>>(ei, cntc);
    scan_kernel<<<1, 1024, 0, stream>>>(cntc, offs, curs);
    scatter_kernel<<<(N_EDGES + 255) / 256, 256, 0, stream>>>(ei, curs, ssrc);
    agg_kernel<<<N_NODES, 256, 0, stream>>>(xp, as, ad, offs, cntc, ssrc, batch, bias, gsum, gcnt);
    final_kernel<<<1, 128, 0, stream>>>(gsum, gcnt, fc_w, fc_b, out);
}